// Round 4
// baseline (85.191 us; speedup 1.0000x reference)
//
#include <hip/hip_runtime.h>
#include <hip/hip_bf16.h>
#include <stdint.h>

typedef __bf16 bf16x8 __attribute__((ext_vector_type(8)));
typedef float  f32x4  __attribute__((ext_vector_type(4)));

#define LSE_OFF 60.0f

__device__ __forceinline__ void gload_lds16(const void* gsrc, void* ldst) {
    __builtin_amdgcn_global_load_lds(
        (const __attribute__((address_space(1))) unsigned int*)gsrc,
        (__attribute__((address_space(3))) unsigned int*)ldst,
        16, 0, 0);
}

// ---------------- kernel 1: permute + fp32->bf16 ----------------
// pred[b][n][c][h][w] -> A[m=(b,n,h,w)][c] row-major (K contiguous). Same for gt.
__global__ void convert_perm(const float* __restrict__ pred, const float* __restrict__ gt,
                             __bf16* __restrict__ Ab, __bf16* __restrict__ Bb)
{
    __shared__ __bf16 tile[256 * 17];
    const int slab = blockIdx.x & 511;
    const bool isA = blockIdx.x < 512;
    const float* src = (isA ? pred : gt) + (size_t)slab * 4096;
    __bf16* dst = (isA ? Ab : Bb) + (size_t)slab * 4096;
    const int t = threadIdx.x;
    #pragma unroll
    for (int it = 0; it < 16; ++it) {
        const int e = it * 256 + t;          // c = e>>4, hw = e&15
        tile[(e >> 4) * 17 + (e & 15)] = (__bf16)src[e];
    }
    __syncthreads();
    #pragma unroll
    for (int it = 0; it < 16; ++it) {
        const int o = it * 256 + t;          // hw = o>>8, c = o&255
        dst[(o >> 8) * 256 + (o & 255)] = tile[(o & 255) * 17 + (o >> 8)];
    }
}

// ---------------- kernel 2: fused GEMM + exp-sum + diag ----------------
// Block: 256 i-rows (A in VGPRs: 64 rows/wave), streams 1024 j in 8 steps of 128,
// B double-buffered in LDS with counted-vmcnt prefetch. 8 waves (4 wi x 2 wj).
// amdgpu_waves_per_eu(2,2): 2 waves/SIMD -> 256-reg budget/wave; working set
// (pfr 128 VGPR + acc 64 AGPR + frags/addr ~32) fits with NO spill.
__global__ __launch_bounds__(512) __attribute__((amdgpu_waves_per_eu(2, 2)))
void gemm_lse(const __bf16* __restrict__ Ab, const __bf16* __restrict__ Bb,
              float* __restrict__ rowsum_part, float* __restrict__ diagv)
{
    __shared__ __align__(16) char lds[131072];   // two 64KB B buffers
    const int tid  = threadIdx.x;
    const int lane = tid & 63;
    const int w    = tid >> 6;       // 0..7
    const int wi   = w >> 1;         // 0..3 (i split)
    const int wj   = w & 1;          // 0..1 (j split)
    const int l15  = lane & 15;
    const int lhi  = lane >> 4;

    const int jc = blockIdx.x & 7;   // XCD-pinned j-chunk
    const int ib = blockIdx.x >> 3;
    const int i0 = ib << 8;          // 256 i-rows per block
    const int j0 = jc << 10;         // 1024 j per block

    // ---- A fragments into registers: 64 i-rows/wave, K=256 -> 4ii x 8ks bf16x8 (128 VGPR) ----
    bf16x8 pfr[4][8];
    {
        const char* base = (const char*)Ab + (size_t)(i0 + wi * 64 + l15) * 512 + lhi * 16;
        #pragma unroll
        for (int ii = 0; ii < 4; ++ii)
            #pragma unroll
            for (int ks = 0; ks < 8; ++ks)
                pfr[ii][ks] = *(const bf16x8*)(base + ii * 16 * 512 + ks * 64);
    }

    const char* Bbase = (const char*)Bb + (size_t)j0 * 512;

    // stage one 128j x 256k chunk (64KB) into LDS buffer `buf`; 8 gload_lds/thread
    auto STAGE = [&](int js, int buf) {
        const char* src = Bbase + (size_t)js * 65536;
        char* dst = lds + buf * 65536;
        #pragma unroll
        for (int it = 0; it < 8; ++it) {
            const int ob = it * 8192 + w * 1024;           // wave-uniform LDS dest
            const int ol = ob + lane * 16;
            const int sb = ol ^ (((ol >> 9) & 15) << 4);   // inverse-swizzled global src
            gload_lds16(src + sb, dst + ob);
        }
    };

    float rs[4] = {0.f, 0.f, 0.f, 0.f};

    STAGE(0, 0);

    for (int js = 0; js < 8; ++js) {
        if (js < 7) {
            STAGE(js + 1, (js + 1) & 1);
            asm volatile("s_waitcnt vmcnt(8)" ::: "memory");   // current buf landed; 8 prefetch in flight
        } else {
            asm volatile("s_waitcnt vmcnt(0)" ::: "memory");
        }
        __builtin_amdgcn_s_barrier();

        const char* bufp = lds + (js & 1) * 65536;

        f32x4 acc[4][4];
        #pragma unroll
        for (int ii = 0; ii < 4; ++ii)
            #pragma unroll
            for (int jj = 0; jj < 4; ++jj)
                acc[ii][jj] = (f32x4){0.f, 0.f, 0.f, 0.f};

        #pragma unroll
        for (int ks = 0; ks < 8; ++ks) {
            const int col = ks * 64 + lhi * 16;
            bf16x8 gfr[4];
            #pragma unroll
            for (int jj = 0; jj < 4; ++jj) {
                const int r = wj * 64 + jj * 16 + l15;
                gfr[jj] = *(const bf16x8*)(bufp + r * 512 + (col ^ ((r & 15) << 4)));
            }
            #pragma unroll
            for (int ii = 0; ii < 4; ++ii)
                #pragma unroll
                for (int jj = 0; jj < 4; ++jj)
                    acc[ii][jj] = __builtin_amdgcn_mfma_f32_16x16x32_bf16(
                        gfr[jj], pfr[ii][ks], acc[ii][jj], 0, 0, 0);
        }

        // epilogue BEFORE the tail barrier: reg-only work overlaps other waves' MFMA
        // D col=i (lane&15), D row=j (lhi*4+reg)
        const int ibase = i0 + wi * 64;
        const int jbase = j0 + js * 128 + wj * 64;
        #pragma unroll
        for (int ii = 0; ii < 4; ++ii) {
            float s = 0.f;
            #pragma unroll
            for (int jj = 0; jj < 4; ++jj) {
                const f32x4 a = acc[ii][jj];
                s += __expf(a[0] - LSE_OFF);
                s += __expf(a[1] - LSE_OFF);
                s += __expf(a[2] - LSE_OFF);
                s += __expf(a[3] - LSE_OFF);
                if (ibase + ii * 16 == jbase + jj * 16) {   // diagonal tile (wave-uniform)
                    const int ig = ibase + ii * 16 + l15;
                    const int rb = lhi * 4;
                    if (l15 == rb + 0) diagv[ig] = a[0];
                    if (l15 == rb + 1) diagv[ig] = a[1];
                    if (l15 == rb + 2) diagv[ig] = a[2];
                    if (l15 == rb + 3) diagv[ig] = a[3];
                }
            }
            rs[ii] += s;
        }

        __builtin_amdgcn_s_barrier();   // all waves done reading buf before it is overwritten
    }

    // reduce partial rowsums across the 4 lhi groups; plain store to this block's slice
    #pragma unroll
    for (int ii = 0; ii < 4; ++ii) {
        float v = rs[ii];
        v += __shfl_xor(v, 16);
        v += __shfl_xor(v, 32);
        if (lhi == 0)
            rowsum_part[(size_t)(jc * 2 + wj) * 8192 + i0 + wi * 64 + ii * 16 + l15] = v;
    }
}

// ---------------- kernel 3: single-block final reduce ----------------
__global__ __launch_bounds__(1024) void reduce_final(const float* __restrict__ rowsum_part,
                                                     const float* __restrict__ diagv,
                                                     float* __restrict__ out)
{
    float v = 0.f;
    #pragma unroll
    for (int r = 0; r < 8; ++r) {
        const int i = r * 1024 + threadIdx.x;
        float s = 0.f;
        #pragma unroll
        for (int p = 0; p < 16; ++p) s += rowsum_part[p * 8192 + i];
        v += __logf(s) - diagv[i];
    }
    #pragma unroll
    for (int d = 1; d < 64; d <<= 1) v += __shfl_xor(v, d);
    __shared__ float red[16];
    if ((threadIdx.x & 63) == 0) red[threadIdx.x >> 6] = v;
    __syncthreads();
    if (threadIdx.x == 0) {
        float t = 0.f;
        #pragma unroll
        for (int k = 0; k < 16; ++k) t += red[k];
        out[0] = LSE_OFF + t * (1.0f / 8192.0f);
    }
}

// ---------------- launch ----------------
extern "C" void kernel_launch(void* const* d_in, const int* in_sizes, int n_in,
                              void* d_out, int out_size, void* d_ws, size_t ws_size,
                              hipStream_t stream) {
    const float* pred = (const float*)d_in[0];
    const float* gt   = (const float*)d_in[1];
    float* out = (float*)d_out;

    char* ws = (char*)d_ws;
    float*  rowsum_part = (float*)(ws);            // 16 x 8192 f32 = 512KB (fully written)
    float*  diagv       = (float*)(ws + 0x80000);  // 8192 f32 (fully overwritten)
    __bf16* Ab          = (__bf16*)(ws + 0x90000); // 8192x256 bf16 = 4MB
    __bf16* Bb          = (__bf16*)(ws + 0x490000);// 4MB

    convert_perm<<<1024, 256, 0, stream>>>(pred, gt, Ab, Bb);
    gemm_lse<<<256, 512, 0, stream>>>(Ab, Bb, rowsum_part, diagv);
    reduce_final<<<1, 1024, 0, stream>>>(rowsum_part, diagv, out);
}

// Round 5
// 59.125 us; speedup vs baseline: 1.4409x; 1.4409x over previous
//
#include <hip/hip_runtime.h>
#include <hip/hip_bf16.h>
#include <stdint.h>

typedef __bf16 bf16x8 __attribute__((ext_vector_type(8)));
typedef float  f32x4  __attribute__((ext_vector_type(4)));

#define LOG2E   1.4426950408889634f
#define LN2     0.6931471805599453f
#define LSE_OFF 60.0f
#define C_SCALED (LSE_OFF * LOG2E)   // 86.56170...

__device__ __forceinline__ void gload_lds16(const void* gsrc, void* ldst) {
    __builtin_amdgcn_global_load_lds(
        (const __attribute__((address_space(1))) unsigned int*)gsrc,
        (__attribute__((address_space(3))) unsigned int*)ldst,
        16, 0, 0);
}

// ---------------- kernel 1: permute + fp32->bf16 ----------------
// pred[b][n][c][h][w] -> A[m][c] row-major, SCALED by log2(e) (folds the
// exp->exp2 conversion into the GEMM operand). gt -> B[m][c] unscaled.
__global__ void convert_perm(const float* __restrict__ pred, const float* __restrict__ gt,
                             __bf16* __restrict__ Ab, __bf16* __restrict__ Bb)
{
    __shared__ __bf16 tile[256 * 17];
    const int slab = blockIdx.x & 511;
    const bool isA = blockIdx.x < 512;
    const float scale = isA ? LOG2E : 1.0f;
    const float* src = (isA ? pred : gt) + (size_t)slab * 4096;
    __bf16* dst = (isA ? Ab : Bb) + (size_t)slab * 4096;
    const int t = threadIdx.x;
    #pragma unroll
    for (int it = 0; it < 16; ++it) {
        const int e = it * 256 + t;          // c = e>>4, hw = e&15
        tile[(e >> 4) * 17 + (e & 15)] = (__bf16)(src[e] * scale);
    }
    __syncthreads();
    #pragma unroll
    for (int it = 0; it < 16; ++it) {
        const int o = it * 256 + t;          // hw = o>>8, c = o&255
        dst[(o >> 8) * 256 + (o & 255)] = tile[(o & 255) * 17 + (o >> 8)];
    }
}

// ---------------- kernel 2: fused GEMM + exp2-sum + diag ----------------
// 4-wave blocks (256 thr), tile 256i x 512j. A in VGPRs (64 i-rows/wave),
// B double-buffered in LDS (2x32KB) -> 64KB/block -> 2 blocks/CU: when one
// block drains vmcnt+barrier, the other block's waves keep the MFMA pipe fed.
__global__ __launch_bounds__(256) __attribute__((amdgpu_waves_per_eu(2, 2)))
void gemm_lse(const __bf16* __restrict__ Ab, const __bf16* __restrict__ Bb,
              float* __restrict__ rowsum_part, float* __restrict__ diagy)
{
    __shared__ __align__(16) char lds[65536];   // two 32KB B buffers
    const int tid  = threadIdx.x;
    const int lane = tid & 63;
    const int w    = tid >> 6;       // 0..3 (i split only)
    const int l15  = lane & 15;
    const int lhi  = lane >> 4;

    const int jc = blockIdx.x & 15;  // 16 j-chunks of 512
    const int ib = blockIdx.x >> 4;  // 32 i-blocks of 256
    const int i0 = ib << 8;
    const int j0 = jc << 9;

    // ---- A fragments: 64 i-rows/wave, K=256 -> 4ii x 8ks bf16x8 (128 regs) ----
    bf16x8 pfr[4][8];
    {
        const char* base = (const char*)Ab + (size_t)(i0 + w * 64 + l15) * 512 + lhi * 16;
        #pragma unroll
        for (int ii = 0; ii < 4; ++ii)
            #pragma unroll
            for (int ks = 0; ks < 8; ++ks)
                pfr[ii][ks] = *(const bf16x8*)(base + ii * 16 * 512 + ks * 64);
    }

    const char* Bbase = (const char*)Bb + (size_t)j0 * 512;

    // stage one 64j x 256k chunk (32KB); 8 gload_lds per thread (4 waves x 8 x 1KB)
    auto STAGE = [&](int js, int buf) {
        const char* src = Bbase + (size_t)js * 32768;
        char* dst = lds + buf * 32768;
        #pragma unroll
        for (int it = 0; it < 8; ++it) {
            const int ob = it * 4096 + w * 1024;           // wave-uniform LDS dest
            const int ol = ob + lane * 16;
            const int sb = ol ^ (((ol >> 9) & 15) << 4);   // inverse-swizzled global src
            gload_lds16(src + sb, dst + ob);
        }
    };

    float rs[4] = {0.f, 0.f, 0.f, 0.f};

    STAGE(0, 0);

    for (int js = 0; js < 8; ++js) {
        if (js < 7) {
            STAGE(js + 1, (js + 1) & 1);
            asm volatile("s_waitcnt vmcnt(8)" ::: "memory");   // step js landed; 8 prefetch in flight
        } else {
            asm volatile("s_waitcnt vmcnt(0)" ::: "memory");
        }
        __builtin_amdgcn_s_barrier();

        const char* bufp = lds + (js & 1) * 32768;

        f32x4 acc[4][4];
        #pragma unroll
        for (int ii = 0; ii < 4; ++ii)
            #pragma unroll
            for (int jj = 0; jj < 4; ++jj)
                acc[ii][jj] = (f32x4){0.f, 0.f, 0.f, 0.f};

        __builtin_amdgcn_s_setprio(1);
        #pragma unroll
        for (int ks = 0; ks < 8; ++ks) {
            const int col = ks * 64 + lhi * 16;
            bf16x8 gfr[4];
            #pragma unroll
            for (int jj = 0; jj < 4; ++jj) {
                const int r = jj * 16 + l15;               // all 64 j-rows of the step
                gfr[jj] = *(const bf16x8*)(bufp + r * 512 + (col ^ ((r & 15) << 4)));
            }
            #pragma unroll
            for (int ii = 0; ii < 4; ++ii)
                #pragma unroll
                for (int jj = 0; jj < 4; ++jj)
                    acc[ii][jj] = __builtin_amdgcn_mfma_f32_16x16x32_bf16(
                        gfr[jj], pfr[ii][ks], acc[ii][jj], 0, 0, 0);
        }
        __builtin_amdgcn_s_setprio(0);

        // epilogue (reg-only, prio0): exp2 sums + diagonal capture, overlaps
        // the other resident block's MFMA phase.
        const int ibase = i0 + w * 64;
        const int jbase = j0 + js * 64;
        #pragma unroll
        for (int ii = 0; ii < 4; ++ii) {
            float s = 0.f;
            #pragma unroll
            for (int jj = 0; jj < 4; ++jj) {
                const f32x4 a = acc[ii][jj];
                s += __builtin_amdgcn_exp2f(a[0] - C_SCALED);
                s += __builtin_amdgcn_exp2f(a[1] - C_SCALED);
                s += __builtin_amdgcn_exp2f(a[2] - C_SCALED);
                s += __builtin_amdgcn_exp2f(a[3] - C_SCALED);
                if (ibase + ii * 16 == jbase + jj * 16) {   // diagonal tile (wave-uniform)
                    const int ig = ibase + ii * 16 + l15;
                    const int rb = lhi * 4;
                    if (l15 == rb + 0) diagy[ig] = a[0];
                    if (l15 == rb + 1) diagy[ig] = a[1];
                    if (l15 == rb + 2) diagy[ig] = a[2];
                    if (l15 == rb + 3) diagy[ig] = a[3];
                }
            }
            rs[ii] += s;
        }

        __builtin_amdgcn_s_barrier();   // all waves done reading buf before overwrite
    }

    // reduce partials across the 4 lhi groups; store to [i][slice=jc] layout
    #pragma unroll
    for (int ii = 0; ii < 4; ++ii) {
        float v = rs[ii];
        v += __shfl_xor(v, 16);
        v += __shfl_xor(v, 32);
        if (lhi == 0)
            rowsum_part[(size_t)(i0 + w * 64 + ii * 16 + l15) * 16 + jc] = v;
    }
}

// ---------------- kernel 3: per-row finish + partial block sums ----------------
__global__ __launch_bounds__(1024) void reduce_partial(const float* __restrict__ rowsum_part,
                                                       const float* __restrict__ diagy,
                                                       float* __restrict__ accum)
{
    const int i = blockIdx.x * 1024 + threadIdx.x;
    const f32x4* p = (const f32x4*)(rowsum_part + (size_t)i * 16);
    float s = 0.f;
    #pragma unroll
    for (int k = 0; k < 4; ++k) {
        const f32x4 v = p[k];
        s += (v[0] + v[1]) + (v[2] + v[3]);
    }
    float val = __log2f(s) - diagy[i];
    #pragma unroll
    for (int d = 1; d < 64; d <<= 1) val += __shfl_xor(val, d);
    __shared__ float red[16];
    if ((threadIdx.x & 63) == 0) red[threadIdx.x >> 6] = val;
    __syncthreads();
    if (threadIdx.x == 0) {
        float t = 0.f;
        #pragma unroll
        for (int k = 0; k < 16; ++k) t += red[k];
        atomicAdd(accum, t);
    }
}

__global__ void finalize(const float* __restrict__ accum, float* __restrict__ out)
{
    out[0] = LSE_OFF + LN2 * accum[0] * (1.0f / 8192.0f);
}

// ---------------- launch ----------------
extern "C" void kernel_launch(void* const* d_in, const int* in_sizes, int n_in,
                              void* d_out, int out_size, void* d_ws, size_t ws_size,
                              hipStream_t stream) {
    const float* pred = (const float*)d_in[0];
    const float* gt   = (const float*)d_in[1];
    float* out = (float*)d_out;

    char* ws = (char*)d_ws;
    float*  accum       = (float*)(ws);             // 1 f32 (zeroed each call)
    float*  diagy       = (float*)(ws + 0x1000);    // 8192 f32 (fully overwritten)
    float*  rowsum_part = (float*)(ws + 0x10000);   // 8192 x 16 f32 = 512KB (fully written)
    __bf16* Ab          = (__bf16*)(ws + 0x100000); // 4MB
    __bf16* Bb          = (__bf16*)(ws + 0x500000); // 4MB

    hipMemsetAsync(accum, 0, 4, stream);

    convert_perm<<<1024, 256, 0, stream>>>(pred, gt, Ab, Bb);
    gemm_lse<<<512, 256, 0, stream>>>(Ab, Bb, rowsum_part, diagy);
    reduce_partial<<<8, 1024, 0, stream>>>(rowsum_part, diagy, accum);
    finalize<<<1, 1, 0, stream>>>(accum, out);
}

// Round 6
// 50.633 us; speedup vs baseline: 1.6825x; 1.1677x over previous
//
#include <hip/hip_runtime.h>
#include <hip/hip_bf16.h>
#include <stdint.h>

typedef __bf16 bf16x8 __attribute__((ext_vector_type(8)));
typedef float  f32x4  __attribute__((ext_vector_type(4)));

#define LOG2E   1.4426950408889634f
#define LN2     0.6931471805599453f
#define LSE_OFF 60.0f
#define C_SCALED (LSE_OFF * LOG2E)   // 86.56170...

__device__ __forceinline__ void gload_lds16(const void* gsrc, void* ldst) {
    __builtin_amdgcn_global_load_lds(
        (const __attribute__((address_space(1))) unsigned int*)gsrc,
        (__attribute__((address_space(3))) unsigned int*)ldst,
        16, 0, 0);
}

// ---------------- kernel 1: permute + fp32->bf16 ----------------
// pred[b][n][c][h][w] -> A[m][c] row-major, SCALED by log2(e). gt -> B[m][c].
__global__ void convert_perm(const float* __restrict__ pred, const float* __restrict__ gt,
                             __bf16* __restrict__ Ab, __bf16* __restrict__ Bb)
{
    __shared__ __bf16 tile[256 * 17];
    const int slab = blockIdx.x & 511;
    const bool isA = blockIdx.x < 512;
    const float scale = isA ? LOG2E : 1.0f;
    const float* src = (isA ? pred : gt) + (size_t)slab * 4096;
    __bf16* dst = (isA ? Ab : Bb) + (size_t)slab * 4096;
    const int t = threadIdx.x;
    #pragma unroll
    for (int it = 0; it < 16; ++it) {
        const int e = it * 256 + t;          // c = e>>4, hw = e&15
        tile[(e >> 4) * 17 + (e & 15)] = (__bf16)(src[e] * scale);
    }
    __syncthreads();
    #pragma unroll
    for (int it = 0; it < 16; ++it) {
        const int o = it * 256 + t;          // hw = o>>8, c = o&255
        dst[(o >> 8) * 256 + (o & 255)] = tile[(o & 255) * 17 + (o >> 8)];
    }
}

// ---------------- kernel 2: fused GEMM + exp2-sum + diag, 4-phase schedule ----------------
// 4-wave blocks (256 thr), tile 256i x 512j, A in VGPRs (64 i-rows/wave),
// B double-buffered in LDS (2x32KB) -> 2 blocks/CU. Each 64j step is split
// into 4 jj-band phases: {8 ds_read ∥ stage-issue -> barrier -> lgkm(0) ->
// setprio(1) 32 MFMA setprio(0) -> 16-exp epilogue}. Per-phase barriers give
// the LDS∥MFMA cross-wave alternation (m201 discipline); phase-sliced exps
// ride the trans pipe under other waves' MFMA.
__global__ __launch_bounds__(256) __attribute__((amdgpu_waves_per_eu(2, 2)))
void gemm_lse(const __bf16* __restrict__ Ab, const __bf16* __restrict__ Bb,
              float* __restrict__ rowsum_part, float* __restrict__ diagy)
{
    __shared__ __align__(16) char lds[65536];   // two 32KB B buffers
    const int tid  = threadIdx.x;
    const int lane = tid & 63;
    const int w    = tid >> 6;       // 0..3 (i split)
    const int l15  = lane & 15;
    const int lhi  = lane >> 4;

    const int jc = blockIdx.x & 15;  // 16 j-chunks of 512 (same jc -> same XCD)
    const int ib = blockIdx.x >> 4;  // 32 i-blocks of 256
    const int i0 = ib << 8;
    const int j0 = jc << 9;

    // ---- A fragments: 64 i-rows/wave, K=256 -> 4ii x 8ks bf16x8 (128 regs) ----
    bf16x8 pfr[4][8];
    {
        const char* base = (const char*)Ab + (size_t)(i0 + w * 64 + l15) * 512 + lhi * 16;
        #pragma unroll
        for (int ii = 0; ii < 4; ++ii)
            #pragma unroll
            for (int ks = 0; ks < 8; ++ks)
                pfr[ii][ks] = *(const bf16x8*)(base + ii * 16 * 512 + ks * 64);
    }

    const char* Bbase = (const char*)Bb + (size_t)j0 * 512;

    // prologue stage of step 0 (8 gload_lds/thread, inverse-swizzled source)
    {
        #pragma unroll
        for (int it = 0; it < 8; ++it) {
            const int ob = it * 4096 + w * 1024;
            const int ol = ob + lane * 16;
            const int sb = ol ^ (((ol >> 9) & 15) << 4);
            gload_lds16(Bbase + sb, lds + ob);
        }
    }

    float rs[4] = {0.f, 0.f, 0.f, 0.f};

    for (int js = 0; js < 8; ++js) {
        // buffer-ready: own stage loads landed (nothing else in flight), then block-wide
        asm volatile("s_waitcnt vmcnt(0)" ::: "memory");
        __builtin_amdgcn_s_barrier();

        const char* bufp = lds + (js & 1) * 32768;
        char*       nbuf = lds + ((js + 1) & 1) * 32768;
        const char* nsrc = Bbase + (size_t)(js + 1) * 32768;
        const int ibase = i0 + w * 64;
        const int jbase = j0 + js * 64;

        #pragma unroll
        for (int jj = 0; jj < 4; ++jj) {
            // --- phase jj: ds_read cluster for j-band [jj*16, jj*16+16) ---
            const int r   = jj * 16 + l15;
            const int rsw = (r & 15) << 4;
            bf16x8 gfr[8];
            #pragma unroll
            for (int ks = 0; ks < 8; ++ks)
                gfr[ks] = *(const bf16x8*)(bufp + r * 512 + ((ks * 64 + lhi * 16) ^ rsw));

            // stage-issue for next step, front-loaded into phases 0 and 1
            if (js < 7 && jj < 2) {
                #pragma unroll
                for (int t = 0; t < 4; ++t) {
                    const int it = jj * 4 + t;
                    const int ob = it * 4096 + w * 1024;
                    const int ol = ob + lane * 16;
                    const int sb = ol ^ (((ol >> 9) & 15) << 4);
                    gload_lds16(nsrc + sb, nbuf + ob);
                }
            }

            __builtin_amdgcn_s_barrier();
            asm volatile("s_waitcnt lgkmcnt(0)" ::: "memory");
            __builtin_amdgcn_sched_barrier(0);

            f32x4 acc[4];
            #pragma unroll
            for (int ii = 0; ii < 4; ++ii) acc[ii] = (f32x4){0.f, 0.f, 0.f, 0.f};

            __builtin_amdgcn_s_setprio(1);
            #pragma unroll
            for (int ks = 0; ks < 8; ++ks)
                #pragma unroll
                for (int ii = 0; ii < 4; ++ii)
                    acc[ii] = __builtin_amdgcn_mfma_f32_16x16x32_bf16(
                        gfr[ks], pfr[ii][ks], acc[ii], 0, 0, 0);
            __builtin_amdgcn_s_setprio(0);

            // --- phase epilogue: 16 exp2 per lane (trans pipe), diag capture ---
            #pragma unroll
            for (int ii = 0; ii < 4; ++ii) {
                const f32x4 a = acc[ii];
                float s = __builtin_amdgcn_exp2f(a[0] - C_SCALED);
                s += __builtin_amdgcn_exp2f(a[1] - C_SCALED);
                s += __builtin_amdgcn_exp2f(a[2] - C_SCALED);
                s += __builtin_amdgcn_exp2f(a[3] - C_SCALED);
                if (ibase + ii * 16 == jbase + jj * 16) {   // diagonal tile (wave-uniform)
                    const int ig = ibase + ii * 16 + l15;
                    const int rb = lhi * 4;
                    if (l15 == rb + 0) diagy[ig] = a[0];
                    if (l15 == rb + 1) diagy[ig] = a[1];
                    if (l15 == rb + 2) diagy[ig] = a[2];
                    if (l15 == rb + 3) diagy[ig] = a[3];
                }
                rs[ii] += s;
            }
        }
    }

    // reduce partials across the 4 lhi groups; store to [i][slice=jc] layout
    #pragma unroll
    for (int ii = 0; ii < 4; ++ii) {
        float v = rs[ii];
        v += __shfl_xor(v, 16);
        v += __shfl_xor(v, 32);
        if (lhi == 0)
            rowsum_part[(size_t)(i0 + w * 64 + ii * 16 + l15) * 16 + jc] = v;
    }
}

// ---------------- kernel 3: per-row finish + per-block partial sums ----------------
__global__ __launch_bounds__(1024) void reduce_partial(const float* __restrict__ rowsum_part,
                                                       const float* __restrict__ diagy,
                                                       float* __restrict__ accum)
{
    const int i = blockIdx.x * 1024 + threadIdx.x;
    const f32x4* p = (const f32x4*)(rowsum_part + (size_t)i * 16);
    float s = 0.f;
    #pragma unroll
    for (int k = 0; k < 4; ++k) {
        const f32x4 v = p[k];
        s += (v[0] + v[1]) + (v[2] + v[3]);
    }
    float val = __log2f(s) - diagy[i];
    #pragma unroll
    for (int d = 1; d < 64; d <<= 1) val += __shfl_xor(val, d);
    __shared__ float red[16];
    if ((threadIdx.x & 63) == 0) red[threadIdx.x >> 6] = val;
    __syncthreads();
    if (threadIdx.x == 0) {
        float t = 0.f;
        #pragma unroll
        for (int k = 0; k < 16; ++k) t += red[k];
        accum[blockIdx.x] = t;     // plain store, no atomics / no memset needed
    }
}

__global__ void finalize(const float* __restrict__ accum, float* __restrict__ out)
{
    float t = 0.f;
    #pragma unroll
    for (int k = 0; k < 8; ++k) t += accum[k];
    out[0] = LSE_OFF + LN2 * t * (1.0f / 8192.0f);
}

// ---------------- launch ----------------
extern "C" void kernel_launch(void* const* d_in, const int* in_sizes, int n_in,
                              void* d_out, int out_size, void* d_ws, size_t ws_size,
                              hipStream_t stream) {
    const float* pred = (const float*)d_in[0];
    const float* gt   = (const float*)d_in[1];
    float* out = (float*)d_out;

    char* ws = (char*)d_ws;
    float*  accum       = (float*)(ws);             // 8 f32 (fully written)
    float*  diagy       = (float*)(ws + 0x1000);    // 8192 f32 (fully overwritten)
    float*  rowsum_part = (float*)(ws + 0x10000);   // 8192 x 16 f32 = 512KB (fully written)
    __bf16* Ab          = (__bf16*)(ws + 0x100000); // 4MB
    __bf16* Bb          = (__bf16*)(ws + 0x500000); // 4MB

    convert_perm<<<1024, 256, 0, stream>>>(pred, gt, Ab, Bb);
    gemm_lse<<<512, 256, 0, stream>>>(Ab, Bb, rowsum_part, diagy);
    reduce_partial<<<8, 1024, 0, stream>>>(rowsum_part, diagy, accum);
    finalize<<<1, 1, 0, stream>>>(accum, out);
}